// Round 4
// baseline (267.887 us; speedup 1.0000x reference)
//
#include <hip/hip_runtime.h>

#define TPB 512
#define EPT 4
#define CHUNK (TPB * EPT)   // 2048 elements per block
#define NSLICE 64           // histogram slices to spread global atomics
#define NW 8                // waves per block

typedef unsigned long long ull;
typedef long long ll;

__device__ __forceinline__ ull shfl_down_u64(ull x, int off) {
    unsigned lo = (unsigned)x, hi = (unsigned)(x >> 32);
    lo = __shfl_down(lo, off, 64);
    hi = __shfl_down(hi, off, 64);
    return ((ull)hi << 32) | lo;
}

// ---------------------------------------------------------------------------
// Pass A: per-element pre-shift compute + histograms + block sums.
// TPB=512/EPT=4: 6 dwordx4 loads per thread (27 live values) so the compiler
// keeps ALL loads in flight across the LDS-init barrier.
// Tail (no spin): partialA[b] plain store + one packed u64 atomicAdd into
// l1sum[b>>5]. Prefix/shift reconstruction happens in pass B's prologue.
// Packed word: [62:39] = v_sum | [38:0] = combined * 16384 (fixed point).
// ---------------------------------------------------------------------------
__global__ __launch_bounds__(TPB, 8) void k_passA(
    const float* __restrict__ blp, const int* __restrict__ st,
    const int* __restrict__ q, const int* __restrict__ fam,
    const int* __restrict__ mic, const int* __restrict__ vm,
    float* __restrict__ out_structural,
    int* __restrict__ ghist, ull* __restrict__ partialA,
    ull* __restrict__ l1sumA, int n)
{
    __shared__ int lh2[2048];    // [0..1023] q64 x 16 rows | [1024..2047] micro64 x 16 rows
    __shared__ int slhs[11];     // 0-3 fam, 4-10 shell
    __shared__ int swv[NW];
    __shared__ float swc[NW];

    const int tid = threadIdx.x, lane = tid & 63, wave = tid >> 6;
    const long i0 = (long)blockIdx.x * CHUNK + (long)tid * EPT;
    const bool fast = ((long)(blockIdx.x + 1) * CHUNK <= n);

    // ---- loads first: 6 dwordx4 in flight during LDS init + barrier ----
    int stv[5], qv[5], fv[5], micv[4], vmv[4];
    float bpv[4];
    if (fast) {
        const int4 sa = *(const int4*)(st + i0);
        const int4 qa = *(const int4*)(q + i0);
        const int4 fa = *(const int4*)(fam + i0);
        const int4 ma = *(const int4*)(mic + i0);
        const int4 va = *(const int4*)(vm + i0);
        const float4 ba = *(const float4*)(blp + i0);
        int nst = __shfl_down(sa.x, 1, 64);
        int nq  = __shfl_down(qa.x, 1, 64);
        int nf  = __shfl_down(fa.x, 1, 64);
        if (lane == 63) {                 // next element lives in the next wave
            const long j = i0 + 4;
            nst = (j < n) ? st[j]  : 0;
            nq  = (j < n) ? q[j]   : 0;
            nf  = (j < n) ? fam[j] : 0;
        }
        stv[0]=sa.x; stv[1]=sa.y; stv[2]=sa.z; stv[3]=sa.w; stv[4]=nst;
        qv[0]=qa.x;  qv[1]=qa.y;  qv[2]=qa.z;  qv[3]=qa.w;  qv[4]=nq;
        fv[0]=fa.x;  fv[1]=fa.y;  fv[2]=fa.z;  fv[3]=fa.w;  fv[4]=nf;
        micv[0]=ma.x; micv[1]=ma.y; micv[2]=ma.z; micv[3]=ma.w;
        vmv[0]=va.x; vmv[1]=va.y; vmv[2]=va.z; vmv[3]=va.w;
        bpv[0]=ba.x; bpv[1]=ba.y; bpv[2]=ba.z; bpv[3]=ba.w;
    } else {
        #pragma unroll
        for (int e = 0; e < 4; ++e) {
            long ii = i0 + e;
            bool r = ii < n;
            stv[e] = r ? st[ii] : 0;  qv[e] = r ? q[ii] : 0;  fv[e] = r ? fam[ii] : 0;
            micv[e] = r ? mic[ii] : 0; vmv[e] = r ? vm[ii] : 0; bpv[e] = r ? blp[ii] : 0.f;
        }
        stv[4] = (i0 + 4 < n) ? st[i0 + 4] : 0;
        qv[4]  = (i0 + 4 < n) ? q[i0 + 4] : 0;
        fv[4]  = (i0 + 4 < n) ? fam[i0 + 4] : 0;
    }

    {   // vectorized LDS zero-init: 4 ints = 1x ds_write_b128 per thread
        int4 z4; z4.x = 0; z4.y = 0; z4.z = 0; z4.w = 0;
        *(int4*)&lh2[tid * 4] = z4;
    }
    if (tid < 11) slhs[tid] = 0;
    __syncthreads();

    const int qrow = ((wave << 1) | (lane & 1)) << 6;        // 16 sub-rows
    int sv = 0;
    float scf = 0.0f;
    ull accF = 0, accS0 = 0, accS1 = 0;
    float structural[4];
    #pragma unroll
    for (int e = 0; e < 4; ++e) {
        int sti = stv[e], qi = qv[e], fi = fv[e], mi = micv[e];
        int v = (vmv[e] != 0);
        int om  = sti & 0xFFF;      int c6  = ((om  >> 6) ^ om ) & 63;
        int omn = stv[e+1] & 0xFFF; int c6n = ((omn >> 6) ^ omn) & 63;
        float d_chi = (float)__popc(c6 ^ c6n) * (1.0f / 6.0f);
        float d_q   = (float)__popc((qi & 63) ^ (qv[e+1] & 63)) * (1.0f / 6.0f);
        int fx = (fi & 3) ^ (fv[e+1] & 3);
        float d_fam = (float)((fx & 1) + ((fx >> 1) & 1)) * 0.5f;
        float score = 0.5f * d_chi + 0.35f * d_q + 0.15f * d_fam;
        score = fminf(fmaxf(score, 1e-6f), 1.0f);
        structural[e] = v ? score : 0.0f;
        float cosine = expf(fminf(bpv[e], 0.0f));
        float combined = 0.5f * (cosine + structural[e]);
        if (v) {
            sv += 1;
            scf += combined;
            atomicAdd(&lh2[qrow + (qi & 63)], 1);
            atomicAdd(&lh2[1024 + qrow + (mi & 63)], 1);
            accF += 1ULL << ((fi & 3) * 16);
            int sh = __popc(c6);
            ull ts = 1ULL << ((sh & 3) * 16);
            if (sh < 4) accS0 += ts; else accS1 += ts;
        }
    }

    if (fast) {
        float4 o;
        o.x=structural[0]; o.y=structural[1]; o.z=structural[2]; o.w=structural[3];
        *(float4*)(out_structural + i0) = o;
    } else {
        #pragma unroll
        for (int e = 0; e < 4; ++e)
            if (i0 + e < n) out_structural[i0 + e] = structural[e];
    }

    #pragma unroll
    for (int off = 32; off > 0; off >>= 1) {
        sv  += __shfl_down(sv, off, 64);
        scf += __shfl_down(scf, off, 64);
        accF  += shfl_down_u64(accF, off);
        accS0 += shfl_down_u64(accS0, off);
        accS1 += shfl_down_u64(accS1, off);
    }
    if (lane == 0) {
        swv[wave] = sv; swc[wave] = scf;
        #pragma unroll
        for (int b2 = 0; b2 < 4; ++b2) atomicAdd(&slhs[b2],     (int)((accF  >> (16*b2)) & 0xFFFF));
        #pragma unroll
        for (int b2 = 0; b2 < 4; ++b2) atomicAdd(&slhs[4 + b2], (int)((accS0 >> (16*b2)) & 0xFFFF));
        #pragma unroll
        for (int b2 = 0; b2 < 3; ++b2) atomicAdd(&slhs[8 + b2], (int)((accS1 >> (16*b2)) & 0xFFFF));
    }
    __syncthreads();

    // publish block partial: plain store (read only after kernel boundary)
    // + one packed u64 atomicAdd into the level-1 group cell.
    if (tid == 0) {
        int vsum = 0; double cs = 0.0;
        #pragma unroll
        for (int w2 = 0; w2 < NW; ++w2) { vsum += swv[w2]; cs += (double)swc[w2]; }
        ll cf = (ll)(cs * 16384.0 + 0.5);
        ull packed = ((ull)(unsigned)vsum << 39) | (ull)cf;
        partialA[blockIdx.x] = packed;
        atomicAdd(&l1sumA[blockIdx.x >> 5], packed);
    }
    // merge bins 0..138 (139..151 derived in B from q_hist64)
    if (tid < 139) {
        int t2 = tid;
        int val;
        if (t2 < 64) {
            val = 0;
            #pragma unroll
            for (int r = 0; r < 16; ++r) val += lh2[(r << 6) + t2];
        } else if (t2 < 68) {
            val = slhs[t2 - 64];
        } else if (t2 < 132) {
            int b2 = t2 - 68;
            val = 0;
            #pragma unroll
            for (int r = 0; r < 16; ++r) val += lh2[1024 + (r << 6) + b2];
        } else {
            val = slhs[4 + (t2 - 132)];
        }
        if (val) atomicAdd(&ghist[(blockIdx.x & (NSLICE - 1)) * 152 + t2], val);
    }
}

// ---------------------------------------------------------------------------
// Pass B: prologue reconstructs pos_offset/total/shift from l1sumA (64 cells)
// + in-group partials (<=31) with plain loads (safe: kernel boundary).
// Main: algebraic sigmoid p/(p+K(1-p)); logp/bmask; run lengths.
// Cross-chunk cummax carry: group-hierarchical publish (atomicMax/Add + done
// counter) and ONE lane-parallel poll round over <=63 group counters and
// <=31 in-group words. Last block emits trailing/patch; block 0 finalizes hist.
// partial2 word: bit63 valid | [45:23] last | [22:0] cnt
// ---------------------------------------------------------------------------
__global__ __launch_bounds__(TPB, 8) void k_passB(
    const float* __restrict__ strc, const float* __restrict__ blp,
    const ull* __restrict__ partialA, const ull* __restrict__ l1sumA,
    const int* __restrict__ ghist,
    ull* __restrict__ partial2, unsigned* __restrict__ l1max2,
    unsigned* __restrict__ l1cnt2, int* __restrict__ grpdone2,
    float* __restrict__ out_logp, float* __restrict__ out_bmask,
    float* __restrict__ out_len, float* __restrict__ out_hist,
    float* __restrict__ out_trailing, float* __restrict__ out_patch, int n)
{
    __shared__ int swt[NW], swm[NW], scnt[NW];
    __shared__ int sCarry, sTV, sPos0;
    __shared__ float sShift;
    __shared__ int qh[64];
    const int tid = threadIdx.x, lane = tid & 63, wave = tid >> 6;
    const long i0 = (long)blockIdx.x * CHUNK + (long)tid * EPT;
    const bool fast = ((long)(blockIdx.x + 1) * CHUNK <= n);
    const int nb = (int)gridDim.x;
    const int b = (int)blockIdx.x;
    const int g = b >> 5, r = b & 31;

    // ---- main loads issued first; prologue hides under their latency ----
    float sv4[4], bp4[4];
    if (fast) {
        const float4 s0 = *(const float4*)(strc + i0);
        const float4 p0 = *(const float4*)(blp + i0);
        sv4[0]=s0.x; sv4[1]=s0.y; sv4[2]=s0.z; sv4[3]=s0.w;
        bp4[0]=p0.x; bp4[1]=p0.y; bp4[2]=p0.z; bp4[3]=p0.w;
    } else {
        #pragma unroll
        for (int e = 0; e < 4; ++e) {
            long ii = i0 + e;
            bool r2 = ii < n;
            sv4[e] = r2 ? strc[ii] : 0.0f;
            bp4[e] = r2 ? blp[ii] : 0.0f;
        }
    }

    // ---- prologue (wave 0): totals + exclusive prefix from hierarchy ----
    if (wave == 0) {
        ull cell = l1sumA[lane];                       // 64 cells, plain load
        int vc = (int)(cell >> 39);
        ll cc = (ll)(cell & ((1ULL << 39) - 1));
        int vex = (lane < g) ? vc : 0;
        if (lane < r) vex += (int)(partialA[(g << 5) + lane] >> 39);
        int vt = vc; ll ct = cc;
        #pragma unroll
        for (int off = 32; off > 0; off >>= 1) {
            vt  += __shfl_down(vt, off, 64);
            vex += __shfl_down(vex, off, 64);
            ct  += (ll)shfl_down_u64((ull)ct, off);
        }
        if (lane == 0) {
            sTV = vt; sPos0 = vex;
            double vcd = (double)(vt > 1 ? vt : 1);
            float cur = (float)(((double)ct * (1.0 / 16384.0)) / vcd);
            cur = fminf(fmaxf(cur, 1e-4f), 0.9999f);
            float p = fminf(fmaxf(cur, 1e-6f), 0.999999f);
            float lc = logf(p) - log1pf(-p);
            float tgt = (float)(1.0 / 6.0);
            float lt = logf(tgt) - log1pf(-tgt);
            sShift = lt - lc;
        }
    }
    __syncthreads();
    const float shift = sShift;
    const float K = expf(-shift);

    unsigned mv = 0, mb = 0;
    float lp[4], bmf[4], lenv[4];
    #pragma unroll
    for (int e = 0; e < 4; ++e) {
        float s = sv4[e];
        int v = (s > 0.0f);                  // structural clipped >= 1e-6 iff valid
        float cosine = expf(fminf(bp4[e], 0.0f));
        float comb = 0.5f * (cosine + s);
        float p = fminf(fmaxf(comb, 1e-6f), 0.999999f);
        float d = fmaf(K, 1.0f - p, p);      // p + K(1-p)
        float sgm = p / d;                   // == sigmoid(logit(p)+shift)
        sgm = fminf(fmaxf(sgm, 1e-6f), 0.999999f);
        float clp = logf(sgm);
        lp[e] = clp;
        int bm = (clp >= -0.69314718f) ? 1 : 0;
        bmf[e] = (float)bm;
        mv |= (unsigned)v << e;
        if (bm & v) mb |= 1u << e;
        lenv[e] = 0.0f;
    }
    if (fast) {
        float4 o;
        o.x=lp[0]; o.y=lp[1]; o.z=lp[2]; o.w=lp[3];     *(float4*)(out_logp + i0) = o;
        o.x=bmf[0]; o.y=bmf[1]; o.z=bmf[2]; o.w=bmf[3]; *(float4*)(out_bmask + i0) = o;
    } else {
        #pragma unroll
        for (int e = 0; e < 4; ++e)
            if (i0 + e < n) { out_logp[i0 + e] = lp[e]; out_bmask[i0 + e] = bmf[e]; }
    }

    // block-wide exclusive valid-count prefix
    int tvc = __popc(mv);
    int x = tvc;
    #pragma unroll
    for (int off = 1; off < 64; off <<= 1) {
        int y = __shfl_up(x, off, 64);
        if (lane >= off) x += y;
    }
    if (lane == 63) swt[wave] = x;
    __syncthreads();
    int wb = sPos0;
    for (int w2 = 0; w2 < wave; ++w2) wb += swt[w2];
    const int vbase = wb + (x - tvc);

    // last-boundary max-scan + cnt reduction
    int last = -1;
    if (mb) {
        int hb = 31 - __clz(mb);
        last = vbase + __popc(mv & ((2u << hb) - 1));
    }
    int m = last;
    #pragma unroll
    for (int off = 1; off < 64; off <<= 1) {
        int y = __shfl_up(m, off, 64);
        if (lane >= off && y > m) m = y;
    }
    int exm = __shfl_up(m, 1, 64);
    if (lane == 0) exm = -1;
    if (lane == 63) swm[wave] = m;
    int cnt = __popc(mb);
    #pragma unroll
    for (int off = 32; off > 0; off >>= 1)
        cnt += __shfl_down(cnt, off, 64);
    if (lane == 0) scnt[wave] = cnt;
    __syncthreads();

    // ---- wave 0: hierarchical publish + one poll round -> carry ----
    if (wave == 0) {
        int Lown = swm[0], Cown = scnt[0];
        #pragma unroll
        for (int w2 = 1; w2 < NW; ++w2) {
            if (swm[w2] > Lown) Lown = swm[w2];
            Cown += scnt[w2];
        }
        if (Lown < 0) Lown = 0;
        if (lane == 0) {
            atomicExch(&partial2[b],
                       (1ULL << 63) | ((ull)(unsigned)Lown << 23) | (ull)(unsigned)Cown);
            atomicMax(&l1max2[g], (unsigned)Lown);
            atomicAdd(&l1cnt2[g], (unsigned)Cown);
            asm volatile("s_waitcnt vmcnt(0)" ::: "memory");  // values land before done++
            atomicAdd(&grpdone2[g], 1);
        }
        // poll: predecessor groups complete + in-group predecessors published
        const bool needG = (lane < g);
        const bool needP = (lane < r);
        int tgtc = 32;
        if (needG) { int t2 = nb - (lane << 5); tgtc = t2 < 32 ? t2 : 32; }
        ull pw = 0;
        for (;;) {
            bool okG = true, okP = true;
            if (needG) okG = (atomicAdd(&grpdone2[lane], 0) >= tgtc);
            if (needP) { pw = atomicAdd(&partial2[(g << 5) + lane], 0ULL); okP = (pw >> 63) != 0; }
            if (__all(okG && okP)) break;
            __builtin_amdgcn_s_sleep(4);
        }
        unsigned gm = needG ? atomicAdd(&l1max2[lane], 0u) : 0u;
        unsigned gc = needG ? atomicAdd(&l1cnt2[lane], 0u) : 0u;
        unsigned pm = needP ? (unsigned)((pw >> 23) & 0x7FFFFFu) : 0u;
        unsigned pc = needP ? (unsigned)(pw & 0x7FFFFFu) : 0u;
        unsigned em = gm > pm ? gm : pm;
        unsigned ec = gc + pc;
        #pragma unroll
        for (int off = 32; off > 0; off >>= 1) {
            unsigned y = __shfl_down(em, off, 64);
            if (y > em) em = y;
            ec += __shfl_down(ec, off, 64);
        }
        if (lane == 0) {
            sCarry = (int)em;
            if (b == nb - 1) {
                int inclM = (int)em > Lown ? (int)em : Lown;
                int trailing = sTV - inclM;
                *out_trailing = (float)trailing;
                *out_patch = (float)((int)ec + Cown + (trailing > 0 ? 1 : 0));
            }
        }
    }
    __syncthreads();

    // run lengths with correct global carry (single write, no fixup pass)
    int prev = sCarry;
    if (exm > prev) prev = exm;
    for (int w2 = 0; w2 < wave; ++w2) if (swm[w2] > prev) prev = swm[w2];
    int runv = 0;
    #pragma unroll
    for (int e = 0; e < 4; ++e) {
        runv += (mv >> e) & 1;
        if ((mb >> e) & 1) {
            int pos = vbase + runv;
            lenv[e] = (float)(pos - prev);
            prev = pos;
        }
    }
    if (fast) {
        float4 o;
        o.x=lenv[0]; o.y=lenv[1]; o.z=lenv[2]; o.w=lenv[3]; *(float4*)(out_len + i0) = o;
    } else {
        #pragma unroll
        for (int e = 0; e < 4; ++e)
            if (i0 + e < n) out_len[i0 + e] = lenv[e];
    }

    // ---- block 0 free tail: histogram finalize ----
    if (b == 0) {
        if (tid < 139) {
            int acc = 0;
            #pragma unroll 8
            for (int sl = 0; sl < NSLICE; ++sl) acc += ghist[sl * 152 + tid];
            out_hist[tid] = (float)acc;
            if (tid < 64) qh[tid] = acc;
        }
        __syncthreads();
        if (tid < 7) {            // q_weight_hist7[w] = sum over bins with popc==w
            int sacc = 0;
            for (int bb = 0; bb < 64; ++bb) if (__popc(bb) == tid) sacc += qh[bb];
            out_hist[139 + tid] = (float)sacc;
        }
        if (tid < 6) {            // bit_excitation6[j] = sum qh[b]*bit_j(b)
            int sacc = 0;
            for (int bb = 0; bb < 64; ++bb) sacc += qh[bb] * ((bb >> tid) & 1);
            out_hist[146 + tid] = (float)sacc;
        }
    }
}

// ---------------------------------------------------------------------------
extern "C" void kernel_launch(void* const* d_in, const int* in_sizes, int n_in,
                              void* d_out, int out_size, void* d_ws, size_t ws_size,
                              hipStream_t stream)
{
    const float* blp = (const float*)d_in[0];
    const int* st   = (const int*)d_in[1];
    const int* q    = (const int*)d_in[2];
    const int* fam  = (const int*)d_in[3];
    const int* mic  = (const int*)d_in[4];
    const int* vm   = (const int*)d_in[5];
    const int n = in_sizes[0];
    const int nb = (n + CHUNK - 1) / CHUNK;          // 2048 for n=4M

    float* out = (float*)d_out;
    float* out_logp       = out;
    float* out_bmask      = out + (size_t)n;
    float* out_structural = out + 2 * (size_t)n;
    float* out_hist       = out + 3 * (size_t)n;     // 152 floats
    float* out_len        = out + 3 * (size_t)n + 152;
    float* out_trailing   = out + 4 * (size_t)n + 152;
    float* out_patch      = out + 4 * (size_t)n + 153;

    char* w = (char*)d_ws;
    int*      ghist    = (int*)(w);                  // 64 x 152 ints      [memset]
    ull*      l1sumA   = (ull*)(w + 38912);          // 64 u64             [memset]
    unsigned* l1max2   = (unsigned*)(w + 39424);     // 64 u32             [memset]
    unsigned* l1cnt2   = (unsigned*)(w + 39680);     // 64 u32             [memset]
    int*      grpdone2 = (int*)(w + 39936);          // 64 int             [memset]
    ull*      partial2 = (ull*)(w + 40960);          // nb u64             [memset]
    ull*      partialA = (ull*)(w + 57344);          // nb u64 (no memset needed)

    hipMemsetAsync(w, 0, 57344, stream);

    k_passA<<<dim3(nb), dim3(TPB), 0, stream>>>(
        blp, st, q, fam, mic, vm, out_structural,
        ghist, partialA, l1sumA, n);

    k_passB<<<dim3(nb), dim3(TPB), 0, stream>>>(
        out_structural, blp, partialA, l1sumA, ghist,
        partial2, l1max2, l1cnt2, grpdone2,
        out_logp, out_bmask, out_len, out_hist, out_trailing, out_patch, n);
}

// Round 5
// 173.365 us; speedup vs baseline: 1.5452x; 1.5452x over previous
//
#include <hip/hip_runtime.h>

#define TPB 256
#define EPT 8
#define CHUNK (TPB * EPT)   // 2048 elements per block
#define P2T 1024            // single-block fixup kernel
#define NSLICE 64           // histogram slices to spread global atomics

typedef unsigned long long ull;
typedef long long ll;

__device__ __forceinline__ ull shfl_down_u64(ull x, int off) {
    unsigned lo = (unsigned)x, hi = (unsigned)(x >> 32);
    lo = __shfl_down(lo, off, 64);
    hi = __shfl_down(hi, off, 64);
    return ((ull)hi << 32) | lo;
}

// ---------------------------------------------------------------------------
// Pass 1: per-element pre-shift compute + histograms + block sums.
// Tail: ONE packed u64 atomicAdd into l1sum[b>>5] (fire-and-forget; no waits,
// no fences). Word: [62:39] = v_sum | [38:0] = combined * 16384 fixed-point.
// ---------------------------------------------------------------------------
__global__ __launch_bounds__(TPB, 8) void k_pass1(
    const float* __restrict__ blp, const int* __restrict__ st,
    const int* __restrict__ q, const int* __restrict__ fam,
    const int* __restrict__ mic, const int* __restrict__ vm,
    float* __restrict__ out_structural,
    int* __restrict__ ghist, ull* __restrict__ l1sum, int n)
{
    __shared__ int lh2[2048];    // [0..1023] q64 x 16 rows | [1024..2047] micro64 x 16 rows
    __shared__ int slhs[11];     // 0-3 fam, 4-10 shell
    __shared__ int swv[4];
    __shared__ float swc[4];

    const int tid = threadIdx.x, lane = tid & 63, wave = tid >> 6;
    const long i0 = (long)blockIdx.x * CHUNK + (long)tid * EPT;
    const bool fast = ((long)(blockIdx.x + 1) * CHUNK <= n);

    // ---- loads first: 12 dwordx4 in flight during LDS init + barrier ----
    int stv[9], qv[9], fv[9], micv[8], vmv[8];
    float bpv[8];
    if (fast) {
        const int4 sa = *(const int4*)(st + i0),  sb = *(const int4*)(st + i0 + 4);
        const int4 qa = *(const int4*)(q + i0),   qb = *(const int4*)(q + i0 + 4);
        const int4 fa = *(const int4*)(fam + i0), fb = *(const int4*)(fam + i0 + 4);
        const int4 ma = *(const int4*)(mic + i0), mb = *(const int4*)(mic + i0 + 4);
        const int4 va = *(const int4*)(vm + i0),  vb = *(const int4*)(vm + i0 + 4);
        const float4 ba = *(const float4*)(blp + i0), bb = *(const float4*)(blp + i0 + 4);
        int nst = __shfl_down(sa.x, 1, 64);
        int nq  = __shfl_down(qa.x, 1, 64);
        int nf  = __shfl_down(fa.x, 1, 64);
        if (lane == 63) {
            const long j = i0 + 8;
            nst = (j < n) ? st[j]  : 0;
            nq  = (j < n) ? q[j]   : 0;
            nf  = (j < n) ? fam[j] : 0;
        }
        stv[0]=sa.x; stv[1]=sa.y; stv[2]=sa.z; stv[3]=sa.w; stv[4]=sb.x; stv[5]=sb.y; stv[6]=sb.z; stv[7]=sb.w; stv[8]=nst;
        qv[0]=qa.x;  qv[1]=qa.y;  qv[2]=qa.z;  qv[3]=qa.w;  qv[4]=qb.x;  qv[5]=qb.y;  qv[6]=qb.z;  qv[7]=qb.w;  qv[8]=nq;
        fv[0]=fa.x;  fv[1]=fa.y;  fv[2]=fa.z;  fv[3]=fa.w;  fv[4]=fb.x;  fv[5]=fb.y;  fv[6]=fb.z;  fv[7]=fb.w;  fv[8]=nf;
        micv[0]=ma.x; micv[1]=ma.y; micv[2]=ma.z; micv[3]=ma.w; micv[4]=mb.x; micv[5]=mb.y; micv[6]=mb.z; micv[7]=mb.w;
        vmv[0]=va.x; vmv[1]=va.y; vmv[2]=va.z; vmv[3]=va.w; vmv[4]=vb.x; vmv[5]=vb.y; vmv[6]=vb.z; vmv[7]=vb.w;
        bpv[0]=ba.x; bpv[1]=ba.y; bpv[2]=ba.z; bpv[3]=ba.w; bpv[4]=bb.x; bpv[5]=bb.y; bpv[6]=bb.z; bpv[7]=bb.w;
    } else {
        #pragma unroll
        for (int e = 0; e < 8; ++e) {
            long ii = i0 + e;
            bool r = ii < n;
            stv[e] = r ? st[ii] : 0;  qv[e] = r ? q[ii] : 0;  fv[e] = r ? fam[ii] : 0;
            micv[e] = r ? mic[ii] : 0; vmv[e] = r ? vm[ii] : 0; bpv[e] = r ? blp[ii] : 0.f;
        }
        stv[8] = (i0 + 8 < n) ? st[i0 + 8] : 0;
        qv[8]  = (i0 + 8 < n) ? q[i0 + 8] : 0;
        fv[8]  = (i0 + 8 < n) ? fam[i0 + 8] : 0;
    }

    {   // vectorized LDS zero-init: 8 ints = 2x ds_write_b128 per thread
        int4 z4; z4.x = 0; z4.y = 0; z4.z = 0; z4.w = 0;
        *(int4*)&lh2[tid * 8] = z4;
        *(int4*)&lh2[tid * 8 + 4] = z4;
    }
    if (tid < 11) slhs[tid] = 0;
    __syncthreads();

    const int qrow = ((wave << 2) | (lane & 3)) << 6;        // 16 sub-rows
    int sv = 0;
    float scf = 0.0f;
    ull accF = 0, accS0 = 0, accS1 = 0;
    float structural[8];
    #pragma unroll
    for (int e = 0; e < 8; ++e) {
        int sti = stv[e], qi = qv[e], fi = fv[e], mi = micv[e];
        int v = (vmv[e] != 0);
        int om  = sti & 0xFFF;      int c6  = ((om  >> 6) ^ om ) & 63;
        int omn = stv[e+1] & 0xFFF; int c6n = ((omn >> 6) ^ omn) & 63;
        float d_chi = (float)__popc(c6 ^ c6n) * (1.0f / 6.0f);
        float d_q   = (float)__popc((qi & 63) ^ (qv[e+1] & 63)) * (1.0f / 6.0f);
        int fx = (fi & 3) ^ (fv[e+1] & 3);
        float d_fam = (float)((fx & 1) + ((fx >> 1) & 1)) * 0.5f;
        float score = 0.5f * d_chi + 0.35f * d_q + 0.15f * d_fam;
        score = fminf(fmaxf(score, 1e-6f), 1.0f);
        structural[e] = v ? score : 0.0f;
        float cosine = expf(fminf(bpv[e], 0.0f));
        float combined = 0.5f * (cosine + structural[e]);
        if (v) {
            sv += 1;
            scf += combined;
            atomicAdd(&lh2[qrow + (qi & 63)], 1);
            atomicAdd(&lh2[1024 + qrow + (mi & 63)], 1);
            accF += 1ULL << ((fi & 3) * 16);
            int sh = __popc(c6);
            ull ts = 1ULL << ((sh & 3) * 16);
            if (sh < 4) accS0 += ts; else accS1 += ts;
        }
    }

    if (fast) {
        float4 o;
        o.x=structural[0]; o.y=structural[1]; o.z=structural[2]; o.w=structural[3];
        *(float4*)(out_structural + i0) = o;
        o.x=structural[4]; o.y=structural[5]; o.z=structural[6]; o.w=structural[7];
        *(float4*)(out_structural + i0 + 4) = o;
    } else {
        #pragma unroll
        for (int e = 0; e < 8; ++e)
            if (i0 + e < n) out_structural[i0 + e] = structural[e];
    }

    #pragma unroll
    for (int off = 32; off > 0; off >>= 1) {
        sv  += __shfl_down(sv, off, 64);
        scf += __shfl_down(scf, off, 64);
        accF  += shfl_down_u64(accF, off);
        accS0 += shfl_down_u64(accS0, off);
        accS1 += shfl_down_u64(accS1, off);
    }
    if (lane == 0) {
        swv[wave] = sv; swc[wave] = scf;
        #pragma unroll
        for (int b2 = 0; b2 < 4; ++b2) atomicAdd(&slhs[b2],     (int)((accF  >> (16*b2)) & 0xFFFF));
        #pragma unroll
        for (int b2 = 0; b2 < 4; ++b2) atomicAdd(&slhs[4 + b2], (int)((accS0 >> (16*b2)) & 0xFFFF));
        #pragma unroll
        for (int b2 = 0; b2 < 3; ++b2) atomicAdd(&slhs[8 + b2], (int)((accS1 >> (16*b2)) & 0xFFFF));
    }
    __syncthreads();
    if (tid == 0) {
        int vsum = swv[0] + swv[1] + swv[2] + swv[3];
        double cs = (double)swc[0] + (double)swc[1] + (double)swc[2] + (double)swc[3];
        ll cf = (ll)(cs * 16384.0 + 0.5);
        atomicAdd(&l1sum[blockIdx.x >> 5], ((ull)(unsigned)vsum << 39) | (ull)cf);
    }
    // merge bins 0..138 (139..151 derived in pass3 from q_hist64)
    if (tid < 139) {
        const int t2 = tid;
        int val;
        if (t2 < 64) {
            val = 0;
            #pragma unroll
            for (int r = 0; r < 16; ++r) val += lh2[(r << 6) + t2];
        } else if (t2 < 68) {
            val = slhs[t2 - 64];
        } else if (t2 < 132) {
            int b2 = t2 - 68;
            val = 0;
            #pragma unroll
            for (int r = 0; r < 16; ++r) val += lh2[1024 + (r << 6) + b2];
        } else {
            val = slhs[4 + (t2 - 132)];
        }
        if (val) atomicAdd(&ghist[(blockIdx.x & (NSLICE - 1)) * 152 + t2], val);
    }
}

// ---------------------------------------------------------------------------
// Pass 3: prologue (wave 0) reduces the 64 l1sum cells -> shift (1 coalesced
// wave-load, ~1us). Algebraic sigmoid p/(p+K(1-p)), K=e^-shift (2 transcend.
// instead of 5). Positions kept LOCAL to the chunk (run lengths are
// translation-invariant; first-in-chunk fixed by pass4, which rebuilds global
// positions from chunk_vsum). Block 0 finalizes the 152-bin histogram.
// ---------------------------------------------------------------------------
__global__ __launch_bounds__(TPB, 8) void k_pass3(
    const float* __restrict__ strc, const float* __restrict__ blp,
    const ull* __restrict__ l1sum, const int* __restrict__ ghist,
    float* __restrict__ out_logp, float* __restrict__ out_bmask,
    float* __restrict__ out_len, int* __restrict__ chunk_cnt,
    int* __restrict__ chunk_lastloc, ull* __restrict__ chunk_first,
    int* __restrict__ chunk_vsum, float* __restrict__ out_hist, int n)
{
    __shared__ int swt[4], swm[4], scnt[4];
    __shared__ float sShift;
    __shared__ int qh[64];
    const int tid = threadIdx.x, lane = tid & 63, wave = tid >> 6;
    const long i0 = (long)blockIdx.x * CHUNK + (long)tid * EPT;
    const bool fast = ((long)(blockIdx.x + 1) * CHUNK <= n);
    const int nb = (int)gridDim.x;

    // ---- main loads issued first; prologue hides under their latency ----
    float sv8[8], bp8[8];
    if (fast) {
        const float4 s0 = *(const float4*)(strc + i0), s1 = *(const float4*)(strc + i0 + 4);
        const float4 p0 = *(const float4*)(blp + i0),  p1 = *(const float4*)(blp + i0 + 4);
        sv8[0]=s0.x; sv8[1]=s0.y; sv8[2]=s0.z; sv8[3]=s0.w; sv8[4]=s1.x; sv8[5]=s1.y; sv8[6]=s1.z; sv8[7]=s1.w;
        bp8[0]=p0.x; bp8[1]=p0.y; bp8[2]=p0.z; bp8[3]=p0.w; bp8[4]=p1.x; bp8[5]=p1.y; bp8[6]=p1.z; bp8[7]=p1.w;
    } else {
        #pragma unroll
        for (int e = 0; e < 8; ++e) {
            long ii = i0 + e;
            bool r = ii < n;
            sv8[e] = r ? strc[ii] : 0.0f;
            bp8[e] = r ? blp[ii] : 0.0f;
        }
    }

    // ---- prologue: wave 0 reduces 64 group cells -> shift ----
    if (wave == 0) {
        const int ngrp = (nb + 31) >> 5;           // 64 for nb=2048
        int vt = 0; ll ct = 0;
        for (int gg = lane; gg < ngrp; gg += 64) {
            ull cell = l1sum[gg];
            vt += (int)(cell >> 39);
            ct += (ll)(cell & ((1ULL << 39) - 1));
        }
        #pragma unroll
        for (int off = 32; off > 0; off >>= 1) {
            vt += __shfl_down(vt, off, 64);
            ct += (ll)shfl_down_u64((ull)ct, off);
        }
        if (lane == 0) {
            double vcd = (double)(vt > 1 ? vt : 1);
            float cur = (float)(((double)ct * (1.0 / 16384.0)) / vcd);
            cur = fminf(fmaxf(cur, 1e-4f), 0.9999f);
            float p = fminf(fmaxf(cur, 1e-6f), 0.999999f);
            float lc = logf(p) - log1pf(-p);
            float tgt = (float)(1.0 / 6.0);
            float lt = logf(tgt) - log1pf(-tgt);
            sShift = lt - lc;
        }
    }
    __syncthreads();
    const float K = expf(-sShift);

    unsigned mv = 0, mb = 0;
    float lp[8], bmf[8], lenv[8];
    #pragma unroll
    for (int e = 0; e < 8; ++e) {
        float s = sv8[e];
        int v = (s > 0.0f);                  // structural clipped >= 1e-6 iff valid
        float cosine = expf(fminf(bp8[e], 0.0f));
        float comb = 0.5f * (cosine + s);
        float p = fminf(fmaxf(comb, 1e-6f), 0.999999f);
        float d = fmaf(K, 1.0f - p, p);      // p + K(1-p)
        float sgm = p / d;                   // == sigmoid(logit(p)+shift)
        sgm = fminf(fmaxf(sgm, 1e-6f), 0.999999f);
        float clp = logf(sgm);
        lp[e] = clp;
        int bm = (clp >= -0.69314718f) ? 1 : 0;
        bmf[e] = (float)bm;
        mv |= (unsigned)v << e;
        if (bm & v) mb |= 1u << e;
        lenv[e] = 0.0f;
    }
    if (fast) {
        float4 o;
        o.x=lp[0]; o.y=lp[1]; o.z=lp[2]; o.w=lp[3];     *(float4*)(out_logp + i0) = o;
        o.x=lp[4]; o.y=lp[5]; o.z=lp[6]; o.w=lp[7];     *(float4*)(out_logp + i0 + 4) = o;
        o.x=bmf[0]; o.y=bmf[1]; o.z=bmf[2]; o.w=bmf[3]; *(float4*)(out_bmask + i0) = o;
        o.x=bmf[4]; o.y=bmf[5]; o.z=bmf[6]; o.w=bmf[7]; *(float4*)(out_bmask + i0 + 4) = o;
    } else {
        #pragma unroll
        for (int e = 0; e < 8; ++e)
            if (i0 + e < n) { out_logp[i0 + e] = lp[e]; out_bmask[i0 + e] = bmf[e]; }
    }

    // block-wide exclusive valid-count prefix (LOCAL: starts at 0)
    int tvc = __popc(mv);
    int x = tvc;
    #pragma unroll
    for (int off = 1; off < 64; off <<= 1) {
        int y = __shfl_up(x, off, 64);
        if (lane >= off) x += y;
    }
    if (lane == 63) swt[wave] = x;
    __syncthreads();
    int wb = 0;
    for (int w2 = 0; w2 < wave; ++w2) wb += swt[w2];
    const int vbase = wb + (x - tvc);          // local (0-based exclusive)

    // last-boundary max-scan + cnt/first reductions (local positions)
    int last = -1;
    if (mb) {
        int hb = 31 - __clz(mb);
        last = vbase + __popc(mv & ((2u << hb) - 1));
    }
    int m = last;
    #pragma unroll
    for (int off = 1; off < 64; off <<= 1) {
        int y = __shfl_up(m, off, 64);
        if (lane >= off && y > m) m = y;
    }
    int exm = __shfl_up(m, 1, 64);
    if (lane == 0) exm = -1;
    if (lane == 63) swm[wave] = m;
    int cnt = __popc(mb);
    ull fp = ~0ULL;
    if (mb) {
        int lb = __ffs(mb) - 1;
        int fv2 = vbase + __popc(mv & ((2u << lb) - 1));   // local 1-indexed
        fp = ((ull)(unsigned)(i0 + lb) << 32) | (unsigned)fv2;
    }
    #pragma unroll
    for (int off = 32; off > 0; off >>= 1) {
        cnt += __shfl_down(cnt, off, 64);
        ull fo = shfl_down_u64(fp, off);
        if (fo < fp) fp = fo;
    }
    __shared__ ull sfirst[4];
    if (lane == 0) { scnt[wave] = cnt; sfirst[wave] = fp; }
    __syncthreads();

    int prev = exm;
    for (int w2 = 0; w2 < wave; ++w2) if (swm[w2] > prev) prev = swm[w2];
    int runv = 0;
    #pragma unroll
    for (int e = 0; e < 8; ++e) {
        runv += (mv >> e) & 1;
        if ((mb >> e) & 1) {
            int pos = vbase + runv;
            lenv[e] = (prev >= 0) ? (float)(pos - prev) : 0.0f;  // first-in-chunk fixed by pass4
            prev = pos;
        }
    }
    if (fast) {
        float4 o;
        o.x=lenv[0]; o.y=lenv[1]; o.z=lenv[2]; o.w=lenv[3]; *(float4*)(out_len + i0) = o;
        o.x=lenv[4]; o.y=lenv[5]; o.z=lenv[6]; o.w=lenv[7]; *(float4*)(out_len + i0 + 4) = o;
    } else {
        #pragma unroll
        for (int e = 0; e < 8; ++e)
            if (i0 + e < n) out_len[i0 + e] = lenv[e];
    }
    if (tid == 0) {
        int c = scnt[0] + scnt[1] + scnt[2] + scnt[3];
        int L = swm[0];
        if (swm[1] > L) L = swm[1];
        if (swm[2] > L) L = swm[2];
        if (swm[3] > L) L = swm[3];
        ull F = sfirst[0];
        if (sfirst[1] < F) F = sfirst[1];
        if (sfirst[2] < F) F = sfirst[2];
        if (sfirst[3] < F) F = sfirst[3];
        chunk_cnt[blockIdx.x] = c;
        chunk_lastloc[blockIdx.x] = L > 0 ? L : 0;   // local 1-indexed, 0 = none
        chunk_first[blockIdx.x] = F;
        chunk_vsum[blockIdx.x] = swt[0] + swt[1] + swt[2] + swt[3];
    }

    // ---- block 0 free tail: histogram finalize ----
    if (blockIdx.x == 0) {
        if (tid < 139) {
            int acc = 0;
            #pragma unroll 8
            for (int sl = 0; sl < NSLICE; ++sl) acc += ghist[sl * 152 + tid];
            out_hist[tid] = (float)acc;
            if (tid < 64) qh[tid] = acc;
        }
        __syncthreads();
        if (tid < 7) {            // q_weight_hist7[w] = sum over bins with popc==w
            int sacc = 0;
            for (int b = 0; b < 64; ++b) if (__popc(b) == tid) sacc += qh[b];
            out_hist[139 + tid] = (float)sacc;
        }
        if (tid < 6) {            // bit_excitation6[j] = sum qh[b]*bit_j(b)
            int sacc = 0;
            for (int b = 0; b < 64; ++b) sacc += qh[b] * ((b >> tid) & 1);
            out_hist[146 + tid] = (float)sacc;
        }
    }
}

// ---------------------------------------------------------------------------
// Pass 4: rebuild global positions from chunk_vsum (sum-scan), global last
// boundaries (max-scan), first-boundary length fix-up, trailing, patch_count.
// 2 chunks/thread, nb <= 2048.
// ---------------------------------------------------------------------------
__global__ __launch_bounds__(P2T) void k_pass4(
    const int* __restrict__ chunk_cnt, const int* __restrict__ chunk_lastloc,
    const ull* __restrict__ chunk_first, const int* __restrict__ chunk_vsum,
    int nb, float* __restrict__ out_len,
    float* __restrict__ out_trailing, float* __restrict__ out_patch)
{
    __shared__ int ss[P2T];   // sum scan (valid counts)
    __shared__ int sm[P2T];   // max scan (global last boundary)
    __shared__ int sc[P2T];   // count reduce
    int t = threadIdx.x;
    int c0 = 2 * t, c1 = 2 * t + 1;
    int v0 = (c0 < nb) ? chunk_vsum[c0] : 0;
    int v1 = (c1 < nb) ? chunk_vsum[c1] : 0;
    int l0 = (c0 < nb) ? chunk_lastloc[c0] : 0;
    int l1 = (c1 < nb) ? chunk_lastloc[c1] : 0;
    int k0 = (c0 < nb) ? chunk_cnt[c0] : 0;
    int k1 = (c1 < nb) ? chunk_cnt[c1] : 0;
    ss[t] = v0 + v1;
    sc[t] = k0 + k1;
    __syncthreads();
    for (int off = 1; off < P2T; off <<= 1) {      // inclusive sum-scan
        int add = (t >= off) ? ss[t - off] : 0;
        __syncthreads();
        ss[t] += add;
        __syncthreads();
    }
    const int vbase0 = ss[t] - v0 - v1;            // exclusive prefix
    const int vbase1 = ss[t] - v1;
    const int total_v = ss[P2T - 1];
    const int gl0 = (l0 > 0) ? vbase0 + l0 : 0;    // global last (1-indexed), 0=none
    const int gl1 = (l1 > 0) ? vbase1 + l1 : 0;
    sm[t] = gl0 > gl1 ? gl0 : gl1;
    __syncthreads();
    for (int off = 1; off < P2T; off <<= 1) {      // inclusive max-scan
        int y = (t >= off) ? sm[t - off] : 0;
        __syncthreads();
        if (y > sm[t]) sm[t] = y;
        __syncthreads();
    }
    const int excl = (t > 0) ? sm[t - 1] : 0;
    if (c0 < nb) {
        ull F = chunk_first[c0];
        if (F != ~0ULL) {
            int fi = (int)(F >> 32);
            int fv = (int)(F & 0xFFFFFFFFu);       // local 1-indexed
            out_len[fi] = (float)(vbase0 + fv - excl);
        }
    }
    const int carry1 = excl > gl0 ? excl : gl0;
    if (c1 < nb) {
        ull F = chunk_first[c1];
        if (F != ~0ULL) {
            int fi = (int)(F >> 32);
            int fv = (int)(F & 0xFFFFFFFFu);
            out_len[fi] = (float)(vbase1 + fv - carry1);
        }
    }
    const int gmax = sm[P2T - 1];
    __syncthreads();
    for (int off = P2T / 2; off > 0; off >>= 1) {  // count reduce
        if (t < off) sc[t] += sc[t + off];
        __syncthreads();
    }
    if (t == 0) {
        int trailing = total_v - gmax;
        *out_trailing = (float)trailing;
        *out_patch = (float)(sc[0] + (trailing > 0 ? 1 : 0));
    }
}

// ---------------------------------------------------------------------------
extern "C" void kernel_launch(void* const* d_in, const int* in_sizes, int n_in,
                              void* d_out, int out_size, void* d_ws, size_t ws_size,
                              hipStream_t stream)
{
    const float* blp = (const float*)d_in[0];
    const int* st   = (const int*)d_in[1];
    const int* q    = (const int*)d_in[2];
    const int* fam  = (const int*)d_in[3];
    const int* mic  = (const int*)d_in[4];
    const int* vm   = (const int*)d_in[5];
    const int n = in_sizes[0];
    const int nb = (n + CHUNK - 1) / CHUNK;          // 2048 for n=4M

    float* out = (float*)d_out;
    float* out_logp       = out;
    float* out_bmask      = out + (size_t)n;
    float* out_structural = out + 2 * (size_t)n;
    float* out_hist       = out + 3 * (size_t)n;     // 152 floats
    float* out_len        = out + 3 * (size_t)n + 152;
    float* out_trailing   = out + 4 * (size_t)n + 152;
    float* out_patch      = out + 4 * (size_t)n + 153;

    char* w = (char*)d_ws;
    int*  ghist         = (int*)(w);                 // 64 x 152 ints   [memset]
    ull*  l1sum         = (ull*)(w + 38912);         // 64 u64          [memset]
    int*  chunk_cnt     = (int*)(w + 40960);         // nb ints
    int*  chunk_lastloc = (int*)(w + 49152);         // nb ints
    int*  chunk_vsum    = (int*)(w + 57344);         // nb ints
    ull*  chunk_first   = (ull*)(w + 65536);         // nb u64

    hipMemsetAsync(w, 0, 39424, stream);             // ghist + l1sum

    k_pass1<<<dim3(nb), dim3(TPB), 0, stream>>>(
        blp, st, q, fam, mic, vm, out_structural, ghist, l1sum, n);

    k_pass3<<<dim3(nb), dim3(TPB), 0, stream>>>(
        out_structural, blp, l1sum, ghist,
        out_logp, out_bmask, out_len, chunk_cnt, chunk_lastloc, chunk_first,
        chunk_vsum, out_hist, n);

    k_pass4<<<dim3(1), dim3(P2T), 0, stream>>>(
        chunk_cnt, chunk_lastloc, chunk_first, chunk_vsum, nb, out_len,
        out_trailing, out_patch);
}